// Round 9
// baseline (62.080 us; speedup 1.0000x reference)
//
#include <hip/hip_runtime.h>
#include <hip/hip_bf16.h>
#include <cstdint>

#define EPS 1e-5f

typedef short bf16x8 __attribute__((ext_vector_type(8)));
typedef float f32x16 __attribute__((ext_vector_type(16)));
typedef unsigned int u32x4 __attribute__((ext_vector_type(4)));

// ws float-offsets
#define WS_TW1S 0       // 16384 ushort: chi-permuted GEMM2 A-frag layout
#define WS_FWQ  8192    // 8192 ushort: GEMM1 A-frag layout [((ks*2+h)*64 + hc)*8 + jj]
#define WS_TB1Q 12288   // 256 floats: [(t*2+hi)*16 + q]
#define WS_W2Q  12544   // 256 floats: [(t*2+hi)*16 + q]
#define WS_FBQ  12800   // 64 floats:  [hi*32 + ht*16 + q]
#define WS_C2   12864   // 8 floats

static __device__ __forceinline__ unsigned short f2bf(float f) {
    unsigned int u = __float_as_uint(f);
    u += 0x7fffu + ((u >> 16) & 1u);   // RNE
    return (unsigned short)(u >> 16);
}
static __device__ __forceinline__ short f2bf_fast(float f) {
    __hip_bfloat16 b = __float2bfloat16(f);
    return __builtin_bit_cast(short, b);
}
static __device__ __forceinline__ unsigned pk_bf16(float lo, float hi) {
    unsigned l = (unsigned)(unsigned short)__builtin_bit_cast(unsigned short, __float2bfloat16(lo));
    unsigned h = (unsigned)(unsigned short)__builtin_bit_cast(unsigned short, __float2bfloat16(hi));
    return l | (h << 16);
}

// Fold both eval-mode BNs; emit bf16 weights in frag-native layouts.
// chi: channel j = ht*32+qq*8+4h+m -> ks = ht*2+(qq>>1), slot = 8h+(qq&1)*4+m
__global__ void tarnet_pre(
    const float* __restrict__ fw, const float* __restrict__ fb,
    const float* __restrict__ f_gamma, const float* __restrict__ f_beta,
    const float* __restrict__ f_mean,  const float* __restrict__ f_var,
    const float* __restrict__ tw1, const float* __restrict__ tb1,
    const float* __restrict__ t_gamma, const float* __restrict__ t_beta,
    const float* __restrict__ t_mean,  const float* __restrict__ t_var,
    const float* __restrict__ tw2, const float* __restrict__ tb2,
    float* __restrict__ ws)
{
    __shared__ float fs[64], fsh[64];
    const int i = threadIdx.x;  // 256 threads
    if (i < 64) {
        float s = f_gamma[i] * rsqrtf(f_var[i] + EPS);
        fs[i]  = s;
        fsh[i] = f_beta[i] - f_mean[i] * s;
    }
    __syncthreads();

    unsigned short* tw1s_u = (unsigned short*)(ws + WS_TW1S);
    unsigned short* fwq_u  = (unsigned short*)(ws + WS_FWQ);

    const int t = i >> 5, r = i & 31;
    const int idx = t * 32 + r;
    {
        float tsc  = t_gamma[idx] * rsqrtf(t_var[idx] + EPS);
        float w2s  = tw2[idx] * tsc;
        float tb1s = tb1[idx];
        for (int j = 0; j < 64; ++j) {
            float w = tw1[idx * 64 + j];
            tb1s += w * fsh[j];
            int ht = j >> 5, qq = (j >> 3) & 3, h = (j >> 2) & 1, m = j & 3;
            int ks = ht * 2 + (qq >> 1);
            int ep = (qq & 1) * 4 + m;
            tw1s_u[(((t*4 + ks)*2 + h)*32 + r)*8 + ep] = f2bf(w * fs[j]);
        }
        int q  = ((r >> 3) << 2) | (r & 3);
        int hq = (r >> 2) & 1;
        ws[WS_TB1Q + (t*2 + hq)*16 + q] = tb1s;
        ws[WS_W2Q  + (t*2 + hq)*16 + q] = w2s;
    }
    if (r == 0) {
        float a = tb2[t];
        for (int rr = 0; rr < 32; ++rr) {
            int id2 = t*32 + rr;
            float ts2 = t_gamma[id2] * rsqrtf(t_var[id2] + EPS);
            a += tw2[id2] * (t_beta[id2] - ts2 * t_mean[id2]);
        }
        ws[WS_C2 + t] = a;
    }
    {   // fw conversion parallelized across all 256 threads (was 1-wave serial)
        const int hc = i >> 2, kq = (i & 3) * 32;
        for (int kk = 0; kk < 32; ++kk) {
            const int k = kq + kk;
            const int ks = k >> 4, h = (k >> 3) & 1, jj = k & 7;
            fwq_u[(((ks*2 + h)*64) + hc)*8 + jj] = f2bf(fw[hc*128 + k]);
        }
    }
    if (i < 64) {
        int ht = i >> 5, r32 = i & 31;
        int q  = ((r32 >> 3) << 2) | (r32 & 3);
        int hq = (r32 >> 2) & 1;
        ws[WS_FBQ + hq*32 + ht*16 + q] = fb[i];
    }
}

#define TILES_PER_BLOCK 4

// 1 wave/block, 32 samples/tile, 4 tiles/block. Wave-private LDS, zero barriers,
// 2-phase software pipeline: loads(t+1) in flight during compute(t).
__global__ __launch_bounds__(64, 2) void tarnet_main(
    const float* __restrict__ x, const int* __restrict__ t_arr,
    const float* __restrict__ ws, float* __restrict__ out)
{
    __shared__ unsigned short xls[32 * 128];   // 8 KB, wave-private, XOR-swizzled
    char* xl = (char*)xls;

    const int lane = threadIdx.x;
    const int ln31 = lane & 31, hi = lane >> 5;
    const int l16  = lane >> 4;       // row sub-offset for staging
    const int pcol = lane & 15;       // 16B column for staging

    const unsigned short* fwq_u  = (const unsigned short*)(ws + WS_FWQ);
    const unsigned short* tw1s_u = (const unsigned short*)(ws + WS_TW1S);

    // hoisted GEMM1 C-init (fb in fragment order)
    float fbi[32];
    {
        const float4* f4 = (const float4*)(ws + WS_FBQ);
#pragma unroll
        for (int i2 = 0; i2 < 8; ++i2) {
            float4 v = f4[hi*8 + i2];
            fbi[4*i2+0] = v.x; fbi[4*i2+1] = v.y;
            fbi[4*i2+2] = v.z; fbi[4*i2+3] = v.w;
        }
    }

    const int tile0 = blockIdx.x * TILES_PER_BLOCK;   // 32-sample tiles

    float4 pf[16];
    {   // prologue: issue tile0's 16 coalesced loads (32B/lane contiguous)
        const float4* src = (const float4*)x + (size_t)tile0 * 1024;
#pragma unroll
        for (int i = 0; i < 8; ++i) {
            pf[2*i]   = src[i*128 + lane*2];
            pf[2*i+1] = src[i*128 + lane*2 + 1];
        }
    }

#pragma unroll
    for (int tt = 0; tt < TILES_PER_BLOCK; ++tt) {
        const int tile = tile0 + tt;
        const int s0 = tile * 32;

        // ---- stage: cvt + swizzled ds_write (consumes pf) ----
#pragma unroll
        for (int i = 0; i < 8; ++i) {
            float4 a = pf[2*i], b = pf[2*i+1];
            bf16x8 v;
            v[0] = f2bf_fast(a.x); v[1] = f2bf_fast(a.y);
            v[2] = f2bf_fast(a.z); v[3] = f2bf_fast(a.w);
            v[4] = f2bf_fast(b.x); v[5] = f2bf_fast(b.y);
            v[6] = f2bf_fast(b.z); v[7] = f2bf_fast(b.w);
            const int row = i*4 + l16;
            *(bf16x8*)(xl + row*256 + ((pcol*16) ^ ((row & 15) << 4))) = v;
        }
        // ---- issue next tile's loads (in flight across compute below) ----
        if (tt + 1 < TILES_PER_BLOCK) {
            const float4* src = (const float4*)x + (size_t)(tile + 1) * 1024;
#pragma unroll
            for (int i = 0; i < 8; ++i) {
                pf[2*i]   = src[i*128 + lane*2];
                pf[2*i+1] = src[i*128 + lane*2 + 1];
            }
        }
        __builtin_amdgcn_sched_barrier(0);   // pin: loads issue BEFORE compute

        const int tsel = t_arr[s0 + ln31];

        // ---- GEMM1: h^T = fw @ x^T (+fb), rows=hc, cols=32 samples ----
        f32x16 acc[2];
#pragma unroll
        for (int ht = 0; ht < 2; ++ht)
#pragma unroll
            for (int q = 0; q < 16; ++q) acc[ht][q] = fbi[ht*16 + q];

        const int rb  = ln31 * 256;
        const int swz = (ln31 & 15) << 4;
#pragma unroll
        for (int ks = 0; ks < 8; ++ks) {
            bf16x8 wa0 = *(const bf16x8*)(fwq_u + (((ks*2 + hi)*64) + ln31     )*8);
            bf16x8 wa1 = *(const bf16x8*)(fwq_u + (((ks*2 + hi)*64) + ln31 + 32)*8);
            bf16x8 xf  = *(const bf16x8*)(xl + rb + ((ks*32 + hi*16) ^ swz));
            acc[0] = __builtin_amdgcn_mfma_f32_32x32x16_bf16(wa0, xf, acc[0], 0, 0, 0);
            acc[1] = __builtin_amdgcn_mfma_f32_32x32x16_bf16(wa1, xf, acc[1], 0, 0, 0);
        }

        // ---- relu -> bf16 pack: lane-local B-frags under chi ----
        bf16x8 hb[4];
        {
            unsigned w0[2][4], w1[2][4];
#pragma unroll
            for (int ht = 0; ht < 2; ++ht)
#pragma unroll
                for (int qq = 0; qq < 4; ++qq) {
                    float a0 = fmaxf(acc[ht][qq*4+0], 0.f);
                    float a1 = fmaxf(acc[ht][qq*4+1], 0.f);
                    float a2 = fmaxf(acc[ht][qq*4+2], 0.f);
                    float a3 = fmaxf(acc[ht][qq*4+3], 0.f);
                    w0[ht][qq] = pk_bf16(a0, a1);
                    w1[ht][qq] = pk_bf16(a2, a3);
                }
#pragma unroll
            for (int ks = 0; ks < 4; ++ks) {
                const int ht = ks >> 1, qa = (ks & 1) * 2;
                u32x4 wv = {w0[ht][qa], w1[ht][qa], w0[ht][qa+1], w1[ht][qa+1]};
                hb[ks] = __builtin_bit_cast(bf16x8, wv);
            }
        }

        // ---- GEMM2 dense over 8 heads: z = tw1s[th] @ h ----
        float outv = 0.f;
#pragma unroll 2
        for (int th = 0; th < 8; ++th) {
            bf16x8 aw[4];
#pragma unroll
            for (int ks = 0; ks < 4; ++ks)
                aw[ks] = *(const bf16x8*)(tw1s_u + (((th*4 + ks)*2 + hi)*32 + ln31)*8);
            float4 tb4[4], w24[4];
#pragma unroll
            for (int i2 = 0; i2 < 4; ++i2) {
                tb4[i2] = ((const float4*)(ws + WS_TB1Q))[(th*2 + hi)*4 + i2];
                w24[i2] = ((const float4*)(ws + WS_W2Q))[(th*2 + hi)*4 + i2];
            }
            const float c2t = ws[WS_C2 + th];
            f32x16 z;
#pragma unroll
            for (int q = 0; q < 16; ++q) z[q] = ((const float*)tb4)[q];
            z = __builtin_amdgcn_mfma_f32_32x32x16_bf16(aw[0], hb[0], z, 0, 0, 0);
            z = __builtin_amdgcn_mfma_f32_32x32x16_bf16(aw[1], hb[1], z, 0, 0, 0);
            z = __builtin_amdgcn_mfma_f32_32x32x16_bf16(aw[2], hb[2], z, 0, 0, 0);
            z = __builtin_amdgcn_mfma_f32_32x32x16_bf16(aw[3], hb[3], z, 0, 0, 0);
            float p0 = 0.f, p1 = 0.f, p2 = 0.f, p3 = 0.f;
#pragma unroll
            for (int q = 0; q < 4; ++q) {
                p0 = fmaf(((const float*)w24)[q],    fmaxf(z[q],    0.f), p0);
                p1 = fmaf(((const float*)w24)[q+4],  fmaxf(z[q+4],  0.f), p1);
                p2 = fmaf(((const float*)w24)[q+8],  fmaxf(z[q+8],  0.f), p2);
                p3 = fmaf(((const float*)w24)[q+12], fmaxf(z[q+12], 0.f), p3);
            }
            float p = (p0 + p1) + (p2 + p3);
            p += __shfl_xor(p, 32);   // other r-half
            p += c2t;
            outv = (th == tsel) ? p : outv;
        }
        if (!hi) out[s0 + ln31] = outv;   // coalesced 32-lane store
    }
}

extern "C" void kernel_launch(void* const* d_in, const int* in_sizes, int n_in,
                              void* d_out, int out_size, void* d_ws, size_t ws_size,
                              hipStream_t stream) {
    const float* x       = (const float*)d_in[0];
    const int*   t       = (const int*)  d_in[1];
    const float* fw      = (const float*)d_in[2];
    const float* fb      = (const float*)d_in[3];
    const float* f_gamma = (const float*)d_in[4];
    const float* f_beta  = (const float*)d_in[5];
    const float* f_mean  = (const float*)d_in[6];
    const float* f_var   = (const float*)d_in[7];
    const float* tw1     = (const float*)d_in[8];
    const float* tb1     = (const float*)d_in[9];
    const float* t_gamma = (const float*)d_in[10];
    const float* t_beta  = (const float*)d_in[11];
    const float* t_mean  = (const float*)d_in[12];
    const float* t_var   = (const float*)d_in[13];
    const float* tw2     = (const float*)d_in[14];
    const float* tb2     = (const float*)d_in[15];

    float* ws   = (float*)d_ws;
    float* outp = (float*)d_out;
    const int B = in_sizes[0] / 128;   // 262144

    tarnet_pre<<<1, 256, 0, stream>>>(fw, fb, f_gamma, f_beta, f_mean, f_var,
                                      tw1, tb1, t_gamma, t_beta, t_mean, t_var,
                                      tw2, tb2, ws);
    const int tiles = B / 32;                          // 8192
    tarnet_main<<<tiles / TILES_PER_BLOCK, 64, 0, stream>>>(x, t, ws, outp);
}